// Round 1
// 473.415 us; speedup vs baseline: 1.0589x; 1.0589x over previous
//
#include <hip/hip_runtime.h>
#include <stdint.h>

// AnyprecisionLinear: out[s,o] = sum_k x[s,k] * lut[o, code(o,k)>>4]
// M=2048, N=8192, K=8192. fp32 in/out, bf16 MFMA compute.
//
// R4 changes vs R3:
//  - gemm_bt rewritten as the 256x256 / BK=64 / 8-wave 4-phase-per-K-tile
//    counted-vmcnt schedule (guide S5 "8-phase template": T2+T3+T4+T5+T1).
//    Back to 16x16x32 MFMA: the chunk-XOR swizzle is conflict-free for the
//    16-row reader (R3's 32x32 reader was a 4-way conflict, 3.35e7 counts).
//    Staging = quarter-tiles (64 rows, 1 global_load_lds per thread), two
//    next-next-tile A-quarters stay in flight across every tile boundary ->
//    s_waitcnt vmcnt(2) in steady state, vmcnt(0) only after the loop.
//  - XCD-aware block swizzle: 256 blocks, each XCD owns one m-row of 32
//    n-tiles -> the 4 MB A-panel is L2-resident per XCD.
//  - dequant / cvt_x unchanged from R3.

#define M_DIM 2048
#define N_DIM 8192
#define K_DIM 8192
#define BM 256
#define BN 256
#define BK 64
#define KT (K_DIM / BK)  // 128 K-tiles

typedef __bf16 bf16x8 __attribute__((ext_vector_type(8)));
typedef float f32x4 __attribute__((ext_vector_type(4)));

__device__ __forceinline__ unsigned int f2bf(float f) {
  // round-to-nearest-even fp32 -> bf16
  unsigned int u = __float_as_uint(f);
  return (u + 0x7FFFu + ((u >> 16) & 1u)) >> 16;
}

// ---------------- dequant: qweight (int32-packed 8-bit codes) -> bf16 W ----
// One wave per output row; block = 4 waves = 4 rows; 2048 blocks.
// LDS: per wave a 4 KB table, entry e / lane l at dword index e*64 + l.
//   byte addr = e*256 + l*4 -> bank = l % 32 (data-independent, conflict-free).
__global__ __launch_bounds__(256) void dequant_kernel(
    const int4* __restrict__ qw4,
    const float* __restrict__ lut,
    unsigned short* __restrict__ wb) {
  __shared__ unsigned int slut[4 * 16 * 64];  // 16 KB
  const int wave = threadIdx.x >> 6;
  const int lane = threadIdx.x & 63;
  const int row = (blockIdx.x << 2) + wave;

  unsigned int* tbl = slut + wave * (16 * 64) + lane;  // this lane's column
  const float* lr = lut + row * 16;
#pragma unroll
  for (int e = 0; e < 16; ++e) tbl[e * 64] = f2bf(lr[e]);

  const int4* src = qw4 + (size_t)row * 512 + lane;  // 512 int4/row
  unsigned short* dst = wb + (size_t)row * K_DIM + lane * 16;

#pragma unroll
  for (int it = 0; it < 8; ++it) {
    int4 q = src[it * 64];
    unsigned int w[4] = {(unsigned int)q.x, (unsigned int)q.y,
                         (unsigned int)q.z, (unsigned int)q.w};
    unsigned int v[16];
#pragma unroll
    for (int j = 0; j < 4; ++j) {
#pragma unroll
      for (int k = 0; k < 4; ++k)
        v[j * 4 + k] = tbl[((w[j] >> (8 * k + 4)) & 15u) * 64];
    }
    uint4 o0, o1;
    o0.x = v[0] | (v[1] << 16);   o0.y = v[2]  | (v[3] << 16);
    o0.z = v[4] | (v[5] << 16);   o0.w = v[6]  | (v[7] << 16);
    o1.x = v[8] | (v[9] << 16);   o1.y = v[10] | (v[11] << 16);
    o1.z = v[12] | (v[13] << 16); o1.w = v[14] | (v[15] << 16);
    uint4* dp = (uint4*)(dst + it * 1024);
    dp[0] = o0;
    dp[1] = o1;
  }
}

// ---------------- x fp32 -> bf16, 8 elements/thread, 16 B stores -----------
__global__ __launch_bounds__(256) void cvt_x_kernel(
    const float4* __restrict__ x4, unsigned int* __restrict__ xb) {
  const int idx = blockIdx.x * 256 + threadIdx.x;
  float4 a = x4[2 * idx];
  float4 b = x4[2 * idx + 1];
  uint4 o;
  o.x = f2bf(a.x) | (f2bf(a.y) << 16);
  o.y = f2bf(a.z) | (f2bf(a.w) << 16);
  o.z = f2bf(b.x) | (f2bf(b.y) << 16);
  o.w = f2bf(b.z) | (f2bf(b.w) << 16);
  ((uint4*)xb)[idx] = o;
}

// ---------------- GEMM: C = A * B^T, 256x256x64 tiles, 8-phase schedule ----
// LDS layout per tile buffer: [256 rows][64 cols] bf16, row = 128 B; 16 B
// chunk-slot s of row r holds global k-chunk s ^ (r&7). Conflict-free for the
// 16x16x32 reader (16 rows -> 8 slots = free 2-way alias).
// A/B operand (16x16x32): row/col = lane&15, k = (lane>>4)*8 + j.
// C/D: col = lane&15, row = (lane>>4)*4 + reg  [m89/m91].

// Stage one 64-row quarter (8 KB, 1 load/thread, 512 thr). LDS dest base is
// wave-uniform (HW adds lane*16). Global source pre-swizzled: lane l of wave w
// fetches row qrow + w*8 + (l>>3), k-chunk (l&7)^(l>>3).
__device__ __forceinline__ void stage_q(const unsigned short* __restrict__ g,
                                        unsigned short* lds_tile, int grow0,
                                        int qrow, int koff, int wave, int srow,
                                        int scol) {
  const unsigned short* src =
      g + (size_t)(grow0 + qrow + (wave << 3) + srow) * K_DIM + koff + scol;
  __builtin_amdgcn_global_load_lds(
      (const __attribute__((address_space(1))) void*)src,
      (__attribute__((address_space(3))) void*)(lds_tile +
                                                (qrow + (wave << 3)) * BK),
      16, 0, 0);
}

__device__ __forceinline__ void load_a4(const unsigned short* __restrict__ s,
                                        int row0, int rrow, int rk,
                                        bf16x8 out[4][2]) {
#pragma unroll
  for (int mi = 0; mi < 4; ++mi) {
    const int row = row0 + mi * 16 + rrow;
    const int sw = row & 7;
#pragma unroll
    for (int ks = 0; ks < 2; ++ks) {
      const int slot = (ks * 4 + rk) ^ sw;
      out[mi][ks] = *(const bf16x8*)(s + row * BK + slot * 8);
    }
  }
}

__device__ __forceinline__ void load_b2(const unsigned short* __restrict__ s,
                                        int row0, int rrow, int rk,
                                        bf16x8 out[2][2]) {
#pragma unroll
  for (int nj = 0; nj < 2; ++nj) {
    const int row = row0 + nj * 16 + rrow;
    const int sw = row & 7;
#pragma unroll
    for (int ks = 0; ks < 2; ++ks) {
      const int slot = (ks * 4 + rk) ^ sw;
      out[nj][ks] = *(const bf16x8*)(s + row * BK + slot * 8);
    }
  }
}

// 16 MFMAs of one quadrant (4 m-frags x 2 n-frags x K=64). ks outer so the
// 8 dependent accumulator updates are 8 issues apart.
#define MFMA_Q(AH, BH)                                                        \
  _Pragma("unroll")                                                           \
  for (int ks = 0; ks < 2; ++ks)                                              \
    _Pragma("unroll")                                                         \
    for (int mi = 0; mi < 4; ++mi)                                            \
      _Pragma("unroll")                                                       \
      for (int nj = 0; nj < 2; ++nj)                                          \
        acc[(AH)*4 + mi][(BH)*2 + nj] =                                       \
            __builtin_amdgcn_mfma_f32_16x16x32_bf16(                          \
                af[mi][ks], bq[nj][ks], acc[(AH)*4 + mi][(BH)*2 + nj], 0, 0, 0);

#define SBAR asm volatile("s_barrier" ::: "memory")

// One K-tile = 4 phases. Quadrant order (AH,BH): (0,0),(0,1),(1,1),(1,0).
// Stage schedule (store-after-last-read verified per quarter):
//   P1: Aq1(t+1), Bq0(t+1) -> other buf      (other buf idle all tile)
//   P2: Aq3(t+1), Bq1(t+1) -> other buf
//   P3: Bq2(t+1), Bq3(t+1) -> other buf
//   P4: Aq0(t+2), Aq2(t+2) -> CURRENT buf    (Aq0/Aq2 last read at P2)
// One s_waitcnt vmcnt(2) per tile (at P4): drains all 8 of tile t+1, keeps
// the two t+2 A-quarters in flight across the boundary. Stage indices wrap
// mod KT so the count stays uniform through the tail (garbage lands in the
// buffer the final tiles don't read; drained by vmcnt(0) after the loop).
#define KTILE(T, BF)                                                          \
  {                                                                           \
    const int ko1 = (((T) + 1) & (KT - 1)) * BK;                              \
    const int ko2 = (((T) + 2) & (KT - 1)) * BK;                              \
    const unsigned short* sa_ = sA[BF];                                       \
    const unsigned short* sb_ = sB[BF];                                       \
    unsigned short* naA = sA[(BF) ^ 1];                                       \
    unsigned short* naB = sB[(BF) ^ 1];                                       \
    unsigned short* caA = sA[BF];                                             \
    /* P1: quad (0,0) */                                                      \
    load_a4(sa_, wm + 0, rrow, rk, af);                                       \
    load_b2(sb_, wn + 0, rrow, rk, bq);                                       \
    stage_q(A, naA, m0, 64, ko1, wave, srow, scol);                           \
    stage_q(B, naB, n0, 0, ko1, wave, srow, scol);                            \
    SBAR;                                                                     \
    __builtin_amdgcn_s_setprio(1);                                            \
    MFMA_Q(0, 0);                                                             \
    __builtin_amdgcn_s_setprio(0);                                            \
    SBAR;                                                                     \
    /* P2: quad (0,1), af reused */                                           \
    load_b2(sb_, wn + 32, rrow, rk, bq);                                      \
    stage_q(A, naA, m0, 192, ko1, wave, srow, scol);                          \
    stage_q(B, naB, n0, 64, ko1, wave, srow, scol);                           \
    SBAR;                                                                     \
    __builtin_amdgcn_s_setprio(1);                                            \
    MFMA_Q(0, 1);                                                             \
    __builtin_amdgcn_s_setprio(0);                                            \
    SBAR;                                                                     \
    /* P3: quad (1,1), bq reused */                                           \
    load_a4(sa_, wm + 64, rrow, rk, af);                                      \
    stage_q(B, naB, n0, 128, ko1, wave, srow, scol);                          \
    stage_q(B, naB, n0, 192, ko1, wave, srow, scol);                          \
    SBAR;                                                                     \
    __builtin_amdgcn_s_setprio(1);                                            \
    MFMA_Q(1, 1);                                                             \
    __builtin_amdgcn_s_setprio(0);                                            \
    SBAR;                                                                     \
    /* P4: quad (1,0), af reused */                                           \
    load_b2(sb_, wn + 0, rrow, rk, bq);                                       \
    stage_q(A, caA, m0, 0, ko2, wave, srow, scol);                            \
    stage_q(A, caA, m0, 128, ko2, wave, srow, scol);                          \
    SBAR;                                                                     \
    __builtin_amdgcn_s_setprio(1);                                            \
    MFMA_Q(1, 0);                                                             \
    __builtin_amdgcn_s_setprio(0);                                            \
    asm volatile("s_waitcnt vmcnt(2)" ::: "memory");                          \
    SBAR;                                                                     \
  }

__global__ __launch_bounds__(512, 2) void gemm_bt(
    const unsigned short* __restrict__ A,
    const unsigned short* __restrict__ B,
    float* __restrict__ C) {
  __shared__ __align__(16) unsigned short sA[2][BM * BK];  // 64 KB
  __shared__ __align__(16) unsigned short sB[2][BN * BK];  // 64 KB

  const int tid = threadIdx.x;
  const int wave = tid >> 6;
  const int lane = tid & 63;

  // XCD swizzle: 256 blocks; XCD c owns m-tile c, n-tiles 0..31 -> the 4 MB
  // A panel is resident in that XCD's L2.
  const int bid = blockIdx.x;
  const int swz = (bid & 7) * 32 + (bid >> 3);
  const int m0 = (swz >> 5) * BM;
  const int n0 = (swz & 31) * BN;

  const int wm = (wave >> 2) * 128;  // 0 or 128
  const int wn = (wave & 3) * 64;    // 0,64,128,192

  // staging lane coords
  const int srow = lane >> 3;                 // 0..7
  const int scol = ((lane & 7) ^ srow) * 8;   // swizzled k-chunk (elements)

  // reader lane coords
  const int rrow = lane & 15;
  const int rk = lane >> 4;  // 0..3

  bf16x8 af[4][2];
  bf16x8 bq[2][2];
  f32x4 acc[8][4];
#pragma unroll
  for (int m = 0; m < 8; ++m)
#pragma unroll
    for (int n = 0; n < 4; ++n)
#pragma unroll
      for (int r = 0; r < 4; ++r) acc[m][n][r] = 0.0f;

  // Prologue: all 8 quarters of tile 0, then Aq0/Aq2 of tile 1 (these two
  // stay in flight, matching the steady-state invariant at loop entry).
  stage_q(A, sA[0], m0, 0, 0, wave, srow, scol);
  stage_q(A, sA[0], m0, 64, 0, wave, srow, scol);
  stage_q(A, sA[0], m0, 128, 0, wave, srow, scol);
  stage_q(A, sA[0], m0, 192, 0, wave, srow, scol);
  stage_q(B, sB[0], n0, 0, 0, wave, srow, scol);
  stage_q(B, sB[0], n0, 64, 0, wave, srow, scol);
  stage_q(B, sB[0], n0, 128, 0, wave, srow, scol);
  stage_q(B, sB[0], n0, 192, 0, wave, srow, scol);
  stage_q(A, sA[1], m0, 0, BK, wave, srow, scol);
  stage_q(A, sA[1], m0, 128, BK, wave, srow, scol);
  asm volatile("s_waitcnt vmcnt(2)" ::: "memory");
  SBAR;

#pragma unroll 1
  for (int tt = 0; tt < KT / 2; ++tt) {
    KTILE(2 * tt, 0)
    KTILE(2 * tt + 1, 1)
  }
  asm volatile("s_waitcnt vmcnt(0)" ::: "memory");

  // Epilogue: C/D layout col = lane&15, row = (lane>>4)*4 + reg.
  const int crow0 = m0 + wm + 4 * rk;
  const int ccol0 = n0 + wn + rrow;
#pragma unroll
  for (int m = 0; m < 8; ++m)
#pragma unroll
    for (int n = 0; n < 4; ++n)
#pragma unroll
      for (int r = 0; r < 4; ++r)
        C[(size_t)(crow0 + m * 16 + r) * N_DIM + ccol0 + n * 16] =
            acc[m][n][r];
}

// Safety-net fallback (only if ws_size < 160 MB): correct fp32, slow.
__global__ void naive_kernel(const float* __restrict__ x,
                             const int* __restrict__ qw,
                             const float* __restrict__ lut,
                             float* __restrict__ out) {
  int o = blockIdx.x * blockDim.x + threadIdx.x;
  int s = blockIdx.y;
  const float* xr = x + (size_t)s * K_DIM;
  const unsigned int* qr = (const unsigned int*)qw + (size_t)o * (K_DIM / 4);
  const float* l = lut + o * 16;
  float acc = 0.f;
  for (int w = 0; w < K_DIM / 4; ++w) {
    unsigned int q = qr[w];
    acc += xr[w * 4 + 0] * l[(q >> 4) & 15u]
         + xr[w * 4 + 1] * l[(q >> 12) & 15u]
         + xr[w * 4 + 2] * l[(q >> 20) & 15u]
         + xr[w * 4 + 3] * l[(q >> 28) & 15u];
  }
  out[(size_t)s * N_DIM + o] = acc;
}

extern "C" void kernel_launch(void* const* d_in, const int* in_sizes, int n_in,
                              void* d_out, int out_size, void* d_ws,
                              size_t ws_size, hipStream_t stream) {
  const float* x = (const float*)d_in[0];
  const int* qw = (const int*)d_in[1];
  const float* lut = (const float*)d_in[2];
  float* out = (float*)d_out;

  const size_t wb_elems = (size_t)N_DIM * K_DIM;  // 128 MB bf16
  const size_t xb_elems = (size_t)M_DIM * K_DIM;  //  32 MB bf16
  const size_t need = (wb_elems + xb_elems) * sizeof(unsigned short);

  if (ws_size >= need) {
    unsigned short* wb = (unsigned short*)d_ws;
    unsigned short* xb = wb + wb_elems;

    hipLaunchKernelGGL(dequant_kernel, dim3(N_DIM / 4), dim3(256), 0, stream,
                       (const int4*)qw, lut, wb);

    const int n_thr = M_DIM * K_DIM / 8;  // 8 elem/thread
    hipLaunchKernelGGL(cvt_x_kernel, dim3(n_thr / 256), dim3(256), 0, stream,
                       (const float4*)x, (unsigned int*)xb);

    hipLaunchKernelGGL(gemm_bt, dim3((M_DIM / BM) * (N_DIM / BN)), dim3(512),
                       0, stream, xb, wb, out);
  } else {
    dim3 grid(N_DIM / 256, M_DIM);
    hipLaunchKernelGGL(naive_kernel, grid, dim3(256), 0, stream, x, qw, lut,
                       out);
  }
}

// Round 2
// 453.152 us; speedup vs baseline: 1.1062x; 1.0447x over previous
//
#include <hip/hip_runtime.h>
#include <stdint.h>

// AnyprecisionLinear: out[s,o] = sum_k x[s,k] * lut[o, code(o,k)>>4]
// M=2048, N=8192, K=8192. fp32 in/out, bf16 MFMA compute.
//
// R5 changes vs R4 (gemm_bt only; dequant/cvt unchanged):
//  - Wave N-columns remapped to split pairs: wave wgn owns C cols
//    {wgn*32..+31} u {128+wgn*32..+31}. nh=0 phases now read only B rows
//    0-127 (quarters 0,1), nh=1 only rows 128-255 (q2,q3) -> quarter-aligned
//    free/need windows for B (A was already quarter-aligned).
//  - Deep stage schedule: P1 stages B q0,q1(t+1) into the other buffer;
//    P2/P3/P4 stage A q0,q2 / B q2,q3 / A q1,q3 of tile t+2 into the
//    CURRENT buffer right after each quarter's last read. s_waitcnt vmcnt(6)
//    at P4 drains only loads >=3 phases old (HBM latency fully hidden) and
//    keeps 6 of tile t+2 in flight across the boundary — the m201/T4
//    counted-vmcnt invariant R4 failed to achieve (its vmcnt(2) waited on
//    1-phase-old loads = effectively drain-0, hence MfmaUtil stuck at 36%).

#define M_DIM 2048
#define N_DIM 8192
#define K_DIM 8192
#define BM 256
#define BN 256
#define BK 64
#define KT (K_DIM / BK)  // 128 K-tiles

typedef __bf16 bf16x8 __attribute__((ext_vector_type(8)));
typedef float f32x4 __attribute__((ext_vector_type(4)));

__device__ __forceinline__ unsigned int f2bf(float f) {
  // round-to-nearest-even fp32 -> bf16
  unsigned int u = __float_as_uint(f);
  return (u + 0x7FFFu + ((u >> 16) & 1u)) >> 16;
}

// ---------------- dequant: qweight (int32-packed 8-bit codes) -> bf16 W ----
// One wave per output row; block = 4 waves = 4 rows; 2048 blocks.
// LDS: per wave a 4 KB table, entry e / lane l at dword index e*64 + l.
//   byte addr = e*256 + l*4 -> bank = l % 32 (data-independent, conflict-free).
__global__ __launch_bounds__(256) void dequant_kernel(
    const int4* __restrict__ qw4,
    const float* __restrict__ lut,
    unsigned short* __restrict__ wb) {
  __shared__ unsigned int slut[4 * 16 * 64];  // 16 KB
  const int wave = threadIdx.x >> 6;
  const int lane = threadIdx.x & 63;
  const int row = (blockIdx.x << 2) + wave;

  unsigned int* tbl = slut + wave * (16 * 64) + lane;  // this lane's column
  const float* lr = lut + row * 16;
#pragma unroll
  for (int e = 0; e < 16; ++e) tbl[e * 64] = f2bf(lr[e]);

  const int4* src = qw4 + (size_t)row * 512 + lane;  // 512 int4/row
  unsigned short* dst = wb + (size_t)row * K_DIM + lane * 16;

#pragma unroll
  for (int it = 0; it < 8; ++it) {
    int4 q = src[it * 64];
    unsigned int w[4] = {(unsigned int)q.x, (unsigned int)q.y,
                         (unsigned int)q.z, (unsigned int)q.w};
    unsigned int v[16];
#pragma unroll
    for (int j = 0; j < 4; ++j) {
#pragma unroll
      for (int k = 0; k < 4; ++k)
        v[j * 4 + k] = tbl[((w[j] >> (8 * k + 4)) & 15u) * 64];
    }
    uint4 o0, o1;
    o0.x = v[0] | (v[1] << 16);   o0.y = v[2]  | (v[3] << 16);
    o0.z = v[4] | (v[5] << 16);   o0.w = v[6]  | (v[7] << 16);
    o1.x = v[8] | (v[9] << 16);   o1.y = v[10] | (v[11] << 16);
    o1.z = v[12] | (v[13] << 16); o1.w = v[14] | (v[15] << 16);
    uint4* dp = (uint4*)(dst + it * 1024);
    dp[0] = o0;
    dp[1] = o1;
  }
}

// ---------------- x fp32 -> bf16, 8 elements/thread, 16 B stores -----------
__global__ __launch_bounds__(256) void cvt_x_kernel(
    const float4* __restrict__ x4, unsigned int* __restrict__ xb) {
  const int idx = blockIdx.x * 256 + threadIdx.x;
  float4 a = x4[2 * idx];
  float4 b = x4[2 * idx + 1];
  uint4 o;
  o.x = f2bf(a.x) | (f2bf(a.y) << 16);
  o.y = f2bf(a.z) | (f2bf(a.w) << 16);
  o.z = f2bf(b.x) | (f2bf(b.y) << 16);
  o.w = f2bf(b.z) | (f2bf(b.w) << 16);
  ((uint4*)xb)[idx] = o;
}

// ---------------- GEMM: C = A * B^T, 256x256x64 tiles, 4-phase K-tiles -----
// LDS per buffer: [256 rows][64 cols] bf16; 16 B chunk-slot s of row r holds
// global k-chunk s ^ (r&7). Conflict-free for the 16x16x32 reader (R4: 0).
// A/B operand (16x16x32): row/col = lane&15, k = (lane>>4)*8 + j.
// C/D: col = lane&15, row = (lane>>4)*4 + reg  [m89/m91].

// Stage one 64-row quarter (8 KB, 1 load/thread, 512 thr). LDS dest base is
// wave-uniform (HW adds lane*16). Global source pre-swizzled: lane l of wave w
// fetches row qrow + w*8 + (l>>3), k-chunk (l&7)^(l>>3).
__device__ __forceinline__ void stage_q(const unsigned short* __restrict__ g,
                                        unsigned short* lds_tile, int grow0,
                                        int qrow, int koff, int wave, int srow,
                                        int scol) {
  const unsigned short* src =
      g + (size_t)(grow0 + qrow + (wave << 3) + srow) * K_DIM + koff + scol;
  __builtin_amdgcn_global_load_lds(
      (const __attribute__((address_space(1))) void*)src,
      (__attribute__((address_space(3))) void*)(lds_tile +
                                                (qrow + (wave << 3)) * BK),
      16, 0, 0);
}

__device__ __forceinline__ void load_a4(const unsigned short* __restrict__ s,
                                        int row0, int rrow, int rk,
                                        bf16x8 out[4][2]) {
#pragma unroll
  for (int mi = 0; mi < 4; ++mi) {
    const int row = row0 + mi * 16 + rrow;
    const int sw = row & 7;
#pragma unroll
    for (int ks = 0; ks < 2; ++ks) {
      const int slot = (ks * 4 + rk) ^ sw;
      out[mi][ks] = *(const bf16x8*)(s + row * BK + slot * 8);
    }
  }
}

__device__ __forceinline__ void load_b2(const unsigned short* __restrict__ s,
                                        int row0, int rrow, int rk,
                                        bf16x8 out[2][2]) {
#pragma unroll
  for (int nj = 0; nj < 2; ++nj) {
    const int row = row0 + nj * 16 + rrow;
    const int sw = row & 7;
#pragma unroll
    for (int ks = 0; ks < 2; ++ks) {
      const int slot = (ks * 4 + rk) ^ sw;
      out[nj][ks] = *(const bf16x8*)(s + row * BK + slot * 8);
    }
  }
}

// 16 MFMAs of one quadrant (4 m-frags x 2 n-frags x K=64). ks outer so the
// 8 dependent accumulator updates are 8 issues apart.
#define MFMA_Q(AH, BH)                                                        \
  _Pragma("unroll")                                                           \
  for (int ks = 0; ks < 2; ++ks)                                              \
    _Pragma("unroll")                                                         \
    for (int mi = 0; mi < 4; ++mi)                                            \
      _Pragma("unroll")                                                       \
      for (int nj = 0; nj < 2; ++nj)                                          \
        acc[(AH)*4 + mi][(BH)*2 + nj] =                                       \
            __builtin_amdgcn_mfma_f32_16x16x32_bf16(                          \
                af[mi][ks], bq[nj][ks], acc[(AH)*4 + mi][(BH)*2 + nj], 0, 0, 0);

#define SBAR asm volatile("s_barrier" ::: "memory")

// One K-tile = 4 phases, quadrants (mh,nh) = (0,0),(0,1),(1,1),(1,0).
// Quarter free times in tile t (store-after-last-read, barrier-separated):
//   A q0,q2: after P1.  B q2,q3: after P2.  A q1,q3: after P3.
//   B q0,q1 of the OTHER buffer: after t-1.P4.
// Stage schedule (8 loads/tile, 14 outstanding max):
//   P1: B q0,q1 (t+1) -> other buf
//   P2: A q0,q2 (t+2) -> current buf
//   P3: B q2,q3 (t+2) -> current buf
//   P4: A q1,q3 (t+2) -> current buf; s_waitcnt vmcnt(6)
// The vmcnt(6) drains exactly tile t+1's 8 loads (ages 3-6 phases: HBM
// latency fully hidden) and keeps tile t+2's 6 in flight across the
// boundary. Stage k-offsets wrap mod KT so the count stays uniform through
// the tail (wrapped garbage lands after last read, never read again).
#define KTILE(T, BF)                                                          \
  {                                                                           \
    const int ko1 = (((T) + 1) & (KT - 1)) * BK;                              \
    const int ko2 = (((T) + 2) & (KT - 1)) * BK;                              \
    const unsigned short* sa_ = sA[BF];                                       \
    const unsigned short* sb_ = sB[BF];                                       \
    unsigned short* naB = sB[(BF) ^ 1];                                       \
    unsigned short* caA = sA[BF];                                             \
    unsigned short* caB = sB[BF];                                             \
    /* P1: quad (0,0) */                                                      \
    load_a4(sa_, wm + 0, rrow, rk, af);                                       \
    load_b2(sb_, bnlo, rrow, rk, bq);                                         \
    stage_q(B, naB, n0, 0, ko1, wave, srow, scol);                            \
    stage_q(B, naB, n0, 64, ko1, wave, srow, scol);                           \
    asm volatile("s_waitcnt lgkmcnt(8)" ::: "memory");                        \
    SBAR;                                                                     \
    __builtin_amdgcn_s_setprio(1);                                            \
    MFMA_Q(0, 0);                                                             \
    __builtin_amdgcn_s_setprio(0);                                            \
    SBAR;                                                                     \
    /* P2: quad (0,1), af reused */                                           \
    load_b2(sb_, bnlo + 128, rrow, rk, bq);                                   \
    stage_q(A, caA, m0, 0, ko2, wave, srow, scol);                            \
    stage_q(A, caA, m0, 128, ko2, wave, srow, scol);                          \
    SBAR;                                                                     \
    __builtin_amdgcn_s_setprio(1);                                            \
    MFMA_Q(0, 1);                                                             \
    __builtin_amdgcn_s_setprio(0);                                            \
    SBAR;                                                                     \
    /* P3: quad (1,1), bq reused */                                           \
    load_a4(sa_, wm + 64, rrow, rk, af);                                      \
    stage_q(B, caB, n0, 128, ko2, wave, srow, scol);                          \
    stage_q(B, caB, n0, 192, ko2, wave, srow, scol);                          \
    SBAR;                                                                     \
    __builtin_amdgcn_s_setprio(1);                                            \
    MFMA_Q(1, 1);                                                             \
    __builtin_amdgcn_s_setprio(0);                                            \
    SBAR;                                                                     \
    /* P4: quad (1,0), af reused */                                           \
    load_b2(sb_, bnlo, rrow, rk, bq);                                         \
    stage_q(A, caA, m0, 64, ko2, wave, srow, scol);                           \
    stage_q(A, caA, m0, 192, ko2, wave, srow, scol);                          \
    SBAR;                                                                     \
    __builtin_amdgcn_s_setprio(1);                                            \
    MFMA_Q(1, 0);                                                             \
    __builtin_amdgcn_s_setprio(0);                                            \
    asm volatile("s_waitcnt vmcnt(6)" ::: "memory");                          \
    SBAR;                                                                     \
  }

__global__ __launch_bounds__(512, 2) void gemm_bt(
    const unsigned short* __restrict__ A,
    const unsigned short* __restrict__ B,
    float* __restrict__ C) {
  __shared__ __align__(16) unsigned short sA[2][BM * BK];  // 64 KB
  __shared__ __align__(16) unsigned short sB[2][BN * BK];  // 64 KB

  const int tid = threadIdx.x;
  const int wave = tid >> 6;
  const int lane = tid & 63;

  // XCD swizzle: 256 blocks; XCD c owns m-tile c, n-tiles 0..31 -> the 4 MB
  // A panel is resident in that XCD's L2.
  const int bid = blockIdx.x;
  const int swz = (bid & 7) * 32 + (bid >> 3);
  const int m0 = (swz >> 5) * BM;
  const int n0 = (swz & 31) * BN;

  const int wm = (wave >> 2) * 128;    // 0 or 128 (M-half)
  const int bnlo = (wave & 3) * 32;    // B row base for nh=0 (nh=1: +128)

  // staging lane coords
  const int srow = lane >> 3;                // 0..7
  const int scol = ((lane & 7) ^ srow) * 8;  // swizzled k-chunk (elements)

  // reader lane coords
  const int rrow = lane & 15;
  const int rk = lane >> 4;  // 0..3

  bf16x8 af[4][2];
  bf16x8 bq[2][2];
  f32x4 acc[8][4];
#pragma unroll
  for (int m = 0; m < 8; ++m)
#pragma unroll
    for (int n = 0; n < 4; ++n)
#pragma unroll
      for (int r = 0; r < 4; ++r) acc[m][n][r] = 0.0f;

  // Prologue: tile 0 fully staged (8 loads), then the steady-state in-flight
  // set for tile 1 in KTILE issue order: A q0,q2; B q2,q3; A q1,q3 (6 loads).
  // B q0,q1 of tile 1 are issued at KTILE(0).P1. vmcnt(6) drains tile 0.
  stage_q(A, sA[0], m0, 0, 0, wave, srow, scol);
  stage_q(A, sA[0], m0, 64, 0, wave, srow, scol);
  stage_q(A, sA[0], m0, 128, 0, wave, srow, scol);
  stage_q(A, sA[0], m0, 192, 0, wave, srow, scol);
  stage_q(B, sB[0], n0, 0, 0, wave, srow, scol);
  stage_q(B, sB[0], n0, 64, 0, wave, srow, scol);
  stage_q(B, sB[0], n0, 128, 0, wave, srow, scol);
  stage_q(B, sB[0], n0, 192, 0, wave, srow, scol);
  stage_q(A, sA[1], m0, 0, BK, wave, srow, scol);
  stage_q(A, sA[1], m0, 128, BK, wave, srow, scol);
  stage_q(B, sB[1], n0, 128, BK, wave, srow, scol);
  stage_q(B, sB[1], n0, 192, BK, wave, srow, scol);
  stage_q(A, sA[1], m0, 64, BK, wave, srow, scol);
  stage_q(A, sA[1], m0, 192, BK, wave, srow, scol);
  asm volatile("s_waitcnt vmcnt(6)" ::: "memory");
  SBAR;

#pragma unroll 1
  for (int tt = 0; tt < KT / 2; ++tt) {
    KTILE(2 * tt, 0)
    KTILE(2 * tt + 1, 1)
  }
  asm volatile("s_waitcnt vmcnt(0)" ::: "memory");

  // Epilogue: C/D layout col = lane&15, row = (lane>>4)*4 + reg.
  // Row for acc[m][.]: wm + (m>>2)*64 + (m&3)*16 == wm + m*16.
  // Col for acc[.][n]: (n>>1)*128 + (wave&3)*32 + (n&1)*16.
  const int crow0 = m0 + wm + 4 * rk;
  const int ccol0 = n0 + bnlo + rrow;
#pragma unroll
  for (int m = 0; m < 8; ++m)
#pragma unroll
    for (int n = 0; n < 4; ++n)
#pragma unroll
      for (int r = 0; r < 4; ++r)
        C[(size_t)(crow0 + m * 16 + r) * N_DIM + ccol0 + (n >> 1) * 128 +
          (n & 1) * 16] = acc[m][n][r];
}

// Safety-net fallback (only if ws_size < 160 MB): correct fp32, slow.
__global__ void naive_kernel(const float* __restrict__ x,
                             const int* __restrict__ qw,
                             const float* __restrict__ lut,
                             float* __restrict__ out) {
  int o = blockIdx.x * blockDim.x + threadIdx.x;
  int s = blockIdx.y;
  const float* xr = x + (size_t)s * K_DIM;
  const unsigned int* qr = (const unsigned int*)qw + (size_t)o * (K_DIM / 4);
  const float* l = lut + o * 16;
  float acc = 0.f;
  for (int w = 0; w < K_DIM / 4; ++w) {
    unsigned int q = qr[w];
    acc += xr[w * 4 + 0] * l[(q >> 4) & 15u]
         + xr[w * 4 + 1] * l[(q >> 12) & 15u]
         + xr[w * 4 + 2] * l[(q >> 20) & 15u]
         + xr[w * 4 + 3] * l[(q >> 28) & 15u];
  }
  out[(size_t)s * N_DIM + o] = acc;
}

extern "C" void kernel_launch(void* const* d_in, const int* in_sizes, int n_in,
                              void* d_out, int out_size, void* d_ws,
                              size_t ws_size, hipStream_t stream) {
  const float* x = (const float*)d_in[0];
  const int* qw = (const int*)d_in[1];
  const float* lut = (const float*)d_in[2];
  float* out = (float*)d_out;

  const size_t wb_elems = (size_t)N_DIM * K_DIM;  // 128 MB bf16
  const size_t xb_elems = (size_t)M_DIM * K_DIM;  //  32 MB bf16
  const size_t need = (wb_elems + xb_elems) * sizeof(unsigned short);

  if (ws_size >= need) {
    unsigned short* wb = (unsigned short*)d_ws;
    unsigned short* xb = wb + wb_elems;

    hipLaunchKernelGGL(dequant_kernel, dim3(N_DIM / 4), dim3(256), 0, stream,
                       (const int4*)qw, lut, wb);

    const int n_thr = M_DIM * K_DIM / 8;  // 8 elem/thread
    hipLaunchKernelGGL(cvt_x_kernel, dim3(n_thr / 256), dim3(256), 0, stream,
                       (const float4*)x, (unsigned int*)xb);

    hipLaunchKernelGGL(gemm_bt, dim3((M_DIM / BM) * (N_DIM / BN)), dim3(512),
                       0, stream, xb, wb, out);
  } else {
    dim3 grid(N_DIM / 256, M_DIM);
    hipLaunchKernelGGL(naive_kernel, grid, dim3(256), 0, stream, x, qw, lut,
                       out);
  }
}